// Round 8
// baseline (141.379 us; speedup 1.0000x reference)
//
#include <hip/hip_runtime.h>

#define S_LEN  4096
#define DM     6
#define NLAYER 4
#define NFF    64
#define HALO   8
#define TPB    256
#define OUT_PER_WAVE 48               // wave holds 64 positions, outputs 48
#define BLK_X 22                      // ceil(ceil(4096/48)=86 waves / 4 per block)

typedef float    vf4 __attribute__((ext_vector_type(4)));
typedef _Float16 vh4 __attribute__((ext_vector_type(4)));

// d_ws frag layouts (dwords). Each entry: 2 f16 halves (j=2*dwj, 2*dwj+1).
// W1A[li][ftile][lane][dwj]: A-frag of W1 (m=f, k=d, d>=6 zero-padded)
// W2A[li][kstep][lane][dwj]: A-frag of W2 (m=d (rows>=6 zero), k=f)
#define W1A_OFF 0
#define W2A_OFF 2048
#define PACK_TOTAL 4096

// wave-private LDS:
//  X: 64 tight 16-B rows [pk01,pk23,pk45,0]; k=6,7 pad stored, k=8..15
//     zeroed at the destination fragment (g>=2).
//  Yt: f32 [6][66] readback (rows 6,7 never read -> dropped; +2 pad)
#define XSZ (64*16)              // 1024 B
#define YSTRIDE 66               // dwords
#define YROWS 6
#define YSZ (YROWS*YSTRIDE*4)    // 1584 B
#define WAVE_LDS (XSZ + YSZ)     // 2608 B -> 10432 B/block

__device__ __forceinline__ unsigned pkh(float a, float b){
    return __builtin_bit_cast(unsigned, __builtin_amdgcn_cvt_pkrtz(a, b));
}
__device__ __forceinline__ unsigned pack2(float lo, float hi){
    _Float16 a = (_Float16)lo, b = (_Float16)hi;
    unsigned short ua = __builtin_bit_cast(unsigned short, a);
    unsigned short ub = __builtin_bit_cast(unsigned short, b);
    return (unsigned)ua | ((unsigned)ub << 16);
}

__global__ void prep_frags(const float* __restrict__ w1,
                           const float* __restrict__ w2,
                           unsigned* __restrict__ ws) {
    int i = blockIdx.x * 256 + threadIdx.x;
    if (i >= PACK_TOTAL) return;
    int which = i >> 11;          // 0=W1A, 1=W2A
    int r  = i & 2047;
    int li = r >> 9;
    int q  = r & 511;
    int tile = q >> 7;            // ftile / kstep
    int rem  = q & 127;
    int lane = rem >> 1;
    int dwj  = rem & 1;
    int c = lane & 15, g = lane >> 4;
    float lo = 0.f, hi = 0.f;
    if (which == 0) {
        int f  = tile*16 + c;
        int d0 = g*4 + 2*dwj;
        if (d0   < DM) lo = w1[li*NFF*DM + f*DM + d0];
        if (d0+1 < DM) hi = w1[li*NFF*DM + f*DM + d0+1];
    } else {
        int d = c;
        int f = tile*16 + g*4 + 2*dwj;
        if (d < DM) { lo = w2[li*DM*NFF + d*NFF + f]; hi = w2[li*DM*NFF + d*NFF + f+1]; }
    }
    ws[i] = pack2(lo, hi);
}

// LayerNorm over 6 scalar f32 elements in registers.
__device__ __forceinline__ void ln6(float* v, const float* __restrict__ w,
                                    const float* __restrict__ b) {
    float mu = (((v[0]+v[1])+(v[2]+v[3]))+(v[4]+v[5])) * (1.0f/6.0f);
    float var = 0.0f;
#pragma unroll
    for (int d = 0; d < DM; ++d) { float dd = v[d]-mu; var = fmaf(dd, dd, var); }
    float r = rsqrtf(fmaf(var, 1.0f/6.0f, 1e-6f));
#pragma unroll
    for (int d = 0; d < DM; ++d) v[d] = fmaf((v[d]-mu)*r, w[d], b[d]);
}

__global__ __launch_bounds__(TPB, 6)
void decoder_fused(const float* __restrict__ x_batch,
                   const float* __restrict__ dec_ln_w, const float* __restrict__ dec_ln_b,
                   const float* __restrict__ qw, const float* __restrict__ qb,
                   const float* __restrict__ kw, const float* __restrict__ kb,
                   const float* __restrict__ vw, const float* __restrict__ vb,
                   const float* __restrict__ mha_ln_w, const float* __restrict__ mha_ln_b,
                   const unsigned* __restrict__ wsp,
                   const float* __restrict__ ffn_b1, const float* __restrict__ ffn_b2,
                   const float* __restrict__ ffn_ln_w, const float* __restrict__ ffn_ln_b,
                   float* __restrict__ out) {
    const int lane = threadIdx.x & 63;
    const int wid  = threadIdx.x >> 6;
    const int w    = blockIdx.x * (TPB/64) + wid;                 // wave index in batch
    if (w * OUT_PER_WAVE - HALO >= S_LEN) return;                 // idle tail waves
    const int b    = blockIdx.y;
    const int p    = w * OUT_PER_WAVE - HALO + lane;              // one position per lane
    const int pc   = min(max(p, 0), S_LEN - 1);
    const int c    = lane & 15, g = lane >> 4;

    __shared__ __align__(16) char smem[(TPB/64) * WAVE_LDS];
    char* wbase = smem + wid * WAVE_LDS;
    char* Xb = wbase;
    char* Yb = wbase + XSZ;

    float x[DM];
    {
        const float2* s = reinterpret_cast<const float2*>(x_batch + ((size_t)b*S_LEN + pc)*DM);
        float2 a0 = s[0], a1 = s[1], a2 = s[2];
        x[0]=a0.x; x[1]=a0.y; x[2]=a1.x; x[3]=a1.y; x[4]=a2.x; x[5]=a2.y;
    }

    ln6(x, dec_ln_w, dec_ln_b);

#pragma unroll 1
    for (int li = 0; li < NLAYER; ++li) {
        // prefetch this layer's FFN frags early (consumed after the mha blocks)
        vh4 w1f[4], w2f[4]; vf4 b1f[4];
#pragma unroll
        for (int mt = 0; mt < 4; ++mt) {
            uint2 u = *((const uint2*)wsp + (li*4 + mt)*64 + lane);
            w1f[mt] = __builtin_bit_cast(vh4, u);
            uint2 v = *((const uint2*)wsp + (W2A_OFF/2) + (li*4 + mt)*64 + lane);
            w2f[mt] = __builtin_bit_cast(vh4, v);
            float4 bb = *reinterpret_cast<const float4*>(ffn_b1 + li*NFF + mt*16 + g*4);
            vf4 bv; bv.x=bb.x; bv.y=bb.y; bv.z=bb.z; bv.w=bb.w;
            b1f[mt] = bv;
        }

        // -------- two mha blocks: barrier-free neighbor exchange via shuffles --------
#pragma unroll 1
        for (int ai = 0; ai < 2; ++ai) {
            const int base = (li*2 + ai) * DM;
            float xm[DM], xp[DM];
#pragma unroll
            for (int d = 0; d < DM; ++d) {
                float up = __shfl_up (x[d], 1);      // pos p-1
                float dn = __shfl_down(x[d], 1);     // pos p+1
                xm[d] = (p <= 0)         ? x[d] : up;   // k_in row0 = itself
                xp[d] = (p >= S_LEN - 1) ? x[d] : dn;   // v_in last row = itself
            }
#pragma unroll
            for (int d = 0; d < DM; ++d) {
                float q = fmaf(x[d],  qw[base+d], qb[base+d]);
                float k = fmaf(xm[d], kw[base+d], kb[base+d]);
                float v = fmaf(xp[d], vw[base+d], vb[base+d]);
                float teo = fmaf(q, q, -(k*v));
                x[d] = fmaf(teo, 1.0f/(float)S_LEN, x[d]);   // softmax(const)=1/S + residual
            }
            ln6(x, mha_ln_w + base, mha_ln_b + base);
        }

        // -------- FFN via per-wave MFMA: Ht = W1·Xt, Yt = W2·relu(Ht+b1) --------
        {
            // stage X: lane's position as one tight 16B row (k=6,7 pad in-store)
            *(uint4*)(Xb + lane*16) = make_uint4(pkh(x[0],x[1]), pkh(x[2],x[3]),
                                                 pkh(x[4],x[5]), 0u);
            // B-frags: k = g*4..g*4+3. g=0 -> dwords 0,1; g=1 -> dwords 2,3
            // (incl. stored zero pad); g>=2 -> k in 8..15 must be ZERO: mask at dest.
            vh4 bfrag[4];
#pragma unroll
            for (int t = 0; t < 4; ++t) {
                vh4 v = *(const vh4*)(Xb + (16*t + c)*16 + (g&1)*8);
                if (g >= 2) v = (vh4)(_Float16)0;
                bfrag[t] = v;
            }

#pragma unroll
            for (int t = 0; t < 4; ++t) {
                vh4 hb[4];
#pragma unroll
                for (int ft = 0; ft < 4; ++ft) {
                    vf4 hc = __builtin_amdgcn_mfma_f32_16x16x16f16(w1f[ft], bfrag[t], b1f[ft], 0, 0, 0);
                    uint2 u = make_uint2(pkh(hc.x,hc.y), pkh(hc.z,hc.w));
                    vh4 hraw = __builtin_bit_cast(vh4, u);
                    vh4 z4 = (vh4)(_Float16)0;
                    hb[ft] = __builtin_elementwise_max(hraw, z4);   // relu in pk-f16
                }
                vf4 yacc; yacc.x=0.f; yacc.y=0.f; yacc.z=0.f; yacc.w=0.f;
#pragma unroll
                for (int ks = 0; ks < 4; ++ks)
                    yacc = __builtin_amdgcn_mfma_f32_16x16x16f16(w2f[ks], hb[ks], yacc, 0, 0, 0);
                int col = 16*t + c;
                float* yp = (float*)Yb;
                if (lane < 32) {                 // rows g*4, g*4+1  (g=1 -> rows 4,5)
                    yp[(g*4+0)*YSTRIDE + col] = yacc.x;
                    yp[(g*4+1)*YSTRIDE + col] = yacc.y;
                }
                if (lane < 16) {                 // rows 2,3 (rows 6,7 dropped)
                    yp[2*YSTRIDE + col] = yacc.z;
                    yp[3*YSTRIDE + col] = yacc.w;
                }
            }
            const float* b2 = ffn_b2 + li*DM;
#pragma unroll
            for (int d = 0; d < DM; ++d)
                x[d] = x[d] + b2[d] + ((float*)Yb)[d*YSTRIDE + lane];
            ln6(x, ffn_ln_w + li*DM, ffn_ln_b + li*DM);
        }
    }

    // lanes 8..55 hold the wave's 48 valid output positions
    if (lane >= HALO && lane < 64 - HALO && p < S_LEN) {
        float2* dst = reinterpret_cast<float2*>(out + ((size_t)b*S_LEN + p)*DM);
        dst[0] = make_float2(x[0], x[1]);
        dst[1] = make_float2(x[2], x[3]);
        dst[2] = make_float2(x[4], x[5]);
    }
}

extern "C" void kernel_launch(void* const* d_in, const int* in_sizes, int n_in,
                              void* d_out, int out_size, void* d_ws, size_t ws_size,
                              hipStream_t stream) {
    const float* x_batch  = (const float*)d_in[0];
    // d_in[1] enc_output: unused by the reference
    const float* dec_ln_w = (const float*)d_in[2];
    const float* dec_ln_b = (const float*)d_in[3];
    const float* qw       = (const float*)d_in[4];
    const float* qb       = (const float*)d_in[5];
    const float* kw       = (const float*)d_in[6];
    const float* kb       = (const float*)d_in[7];
    const float* vw       = (const float*)d_in[8];
    const float* vb       = (const float*)d_in[9];
    // d_in[10..11] ln1_w/ln1_b: dead (softmax of a seq-constant)
    const float* mha_ln_w = (const float*)d_in[12];
    const float* mha_ln_b = (const float*)d_in[13];
    const float* ffn_w1   = (const float*)d_in[14];
    const float* ffn_b1   = (const float*)d_in[15];
    const float* ffn_w2   = (const float*)d_in[16];
    const float* ffn_b2   = (const float*)d_in[17];
    const float* ffn_ln_w = (const float*)d_in[18];
    const float* ffn_ln_b = (const float*)d_in[19];
    float* out = (float*)d_out;
    unsigned* wsp = (unsigned*)d_ws;

    prep_frags<<<(PACK_TOTAL + 255)/256, 256, 0, stream>>>(ffn_w1, ffn_w2, wsp);

    const int B = in_sizes[0] / (S_LEN * DM);   // 128
    dim3 grid(BLK_X, B);
    decoder_fused<<<grid, TPB, 0, stream>>>(
        x_batch, dec_ln_w, dec_ln_b, qw, qb, kw, kb, vw, vb,
        mha_ln_w, mha_ln_b, wsp, ffn_b1, ffn_b2, ffn_ln_w, ffn_ln_b, out);
}